// Round 2
// baseline (835.244 us; speedup 1.0000x reference)
//
#include <hip/hip_runtime.h>

#define D 64          // D_IN == D_OUT
#define D_EDGE 16
#define NEG 0.01f

__device__ __forceinline__ float leaky(float v) { return v > 0.f ? v : NEG * v; }

// ---------------- Kernel 1: per-node precompute ----------------
//   x_t[n] = x[n] @ W2.T          (W2 [64][64])
//   A[n]   = x[n] @ W1[:, :64].T  (W1 [64][80], cols 0..63)
//   r[n]   = sum_j leaky(x[n][j]) * attn[64+j]
__global__ __launch_bounds__(256) void node_kernel(
    const float* __restrict__ x, const float* __restrict__ W1,
    const float* __restrict__ W2, const float* __restrict__ attn,
    float* __restrict__ A, float* __restrict__ xt, float* __restrict__ r, int N_)
{
    __shared__ float w2s[64 * 64];
    __shared__ float w1s[64 * 64];
    __shared__ float ah[64];
    for (int i = threadIdx.x; i < 64 * 64; i += 256) {
        w2s[i] = W2[i];
        int k = i >> 6, j = i & 63;
        w1s[i] = W1[k * 80 + j];
    }
    if (threadIdx.x < 64) ah[threadIdx.x] = attn[64 + threadIdx.x];
    __syncthreads();

    int n = blockIdx.x * 256 + threadIdx.x;
    if (n >= N_) return;

    const float4* x4 = (const float4*)(x + (size_t)n * D);
    float4 xr[16];
#pragma unroll
    for (int i = 0; i < 16; i++) xr[i] = x4[i];

    const float4* w2s4 = (const float4*)w2s;
    const float4* w1s4 = (const float4*)w1s;
    for (int k = 0; k < 64; k++) {
        float a = 0.f, b = 0.f;
#pragma unroll
        for (int j = 0; j < 16; j++) {
            float4 w = w2s4[k * 16 + j];
            a += xr[j].x * w.x + xr[j].y * w.y + xr[j].z * w.z + xr[j].w * w.w;
            float4 u = w1s4[k * 16 + j];
            b += xr[j].x * u.x + xr[j].y * u.y + xr[j].z * u.z + xr[j].w * u.w;
        }
        xt[(size_t)n * D + k] = a;
        A[(size_t)n * D + k]  = b;
    }

    float rr = 0.f;
#pragma unroll
    for (int j = 0; j < 16; j++) {
        rr += leaky(xr[j].x) * ah[4 * j + 0];
        rr += leaky(xr[j].y) * ah[4 * j + 1];
        rr += leaky(xr[j].z) * ah[4 * j + 2];
        rr += leaky(xr[j].w) * ah[4 * j + 3];
    }
    r[n] = rr;
}

// ---------------- CSR build ----------------
__global__ __launch_bounds__(256) void hist_kernel(
    const int* __restrict__ dst, int* __restrict__ counts, int E_)
{
    int e = blockIdx.x * 256 + threadIdx.x;
    if (e < E_) atomicAdd(&counts[dst[e]], 1);
}

// per-block inclusive scan; offs[i+1] = local inclusive, partials[blk] = block sum
__global__ __launch_bounds__(256) void scan1_kernel(
    const int* __restrict__ counts, int* __restrict__ offs,
    int* __restrict__ partials, int N_)
{
    __shared__ int tmp[256];
    int i = blockIdx.x * 256 + threadIdx.x;
    int v = (i < N_) ? counts[i] : 0;
    tmp[threadIdx.x] = v;
    __syncthreads();
    for (int off = 1; off < 256; off <<= 1) {
        int t = (threadIdx.x >= off) ? tmp[threadIdx.x - off] : 0;
        __syncthreads();
        tmp[threadIdx.x] += t;
        __syncthreads();
    }
    if (i < N_) offs[i + 1] = tmp[threadIdx.x];
    if (threadIdx.x == 255) partials[blockIdx.x] = tmp[255];
}

// single block: exclusive scan of partials (nparts <= 512)
__global__ __launch_bounds__(512) void scan2_kernel(int* __restrict__ partials, int nparts)
{
    __shared__ int tmp[512];
    int t = threadIdx.x;
    int v = (t < nparts) ? partials[t] : 0;
    tmp[t] = v;
    __syncthreads();
    for (int off = 1; off < 512; off <<= 1) {
        int a = (t >= off) ? tmp[t - off] : 0;
        __syncthreads();
        tmp[t] += a;
        __syncthreads();
    }
    if (t < nparts) partials[t] = (t > 0) ? tmp[t - 1] : 0;
}

// add block prefix; build cursor[i] = segment start
__global__ __launch_bounds__(256) void scan3_kernel(
    const int* __restrict__ counts, int* __restrict__ offs,
    const int* __restrict__ partials, int* __restrict__ cursor, int N_)
{
    int i = blockIdx.x * 256 + threadIdx.x;
    if (i < N_) {
        int incl = offs[i + 1] + partials[blockIdx.x];
        offs[i + 1] = incl;
        cursor[i] = incl - counts[i];
        if (i == 0) offs[0] = 0;
    }
}

// scatter edges into dst-sorted order
__global__ __launch_bounds__(256) void scatter_kernel(
    const int* __restrict__ src, const int* __restrict__ dst,
    int* __restrict__ cursor, int* __restrict__ srcp, int* __restrict__ eid, int E_)
{
    int e = blockIdx.x * 256 + threadIdx.x;
    if (e < E_) {
        int d = dst[e];
        int j = atomicAdd(&cursor[d], 1);
        srcp[j] = src[e];
        eid[j] = e;
    }
}

// ---------------- Kernel 2: per-edge unnormalized attention ----------------
// wave per edge: p[e] = exp( sum_k leaky(A[src][k] + ea[e]·W1[k,64:80]) * attn[k] + r[dst] )
__global__ __launch_bounds__(256) void p_kernel(
    const float* __restrict__ edge_attr, const int* __restrict__ src,
    const int* __restrict__ dst, const float* __restrict__ W1,
    const float* __restrict__ attn,
    const float* __restrict__ A, const float* __restrict__ r,
    float* __restrict__ p, int E_)
{
    const int lane   = threadIdx.x & 63;
    const int wave   = blockIdx.x * (blockDim.x >> 6) + (threadIdx.x >> 6);
    const int nwaves = gridDim.x * (blockDim.x >> 6);

    const float4* wrow = (const float4*)(W1 + lane * 80 + 64);
    float4 w0 = wrow[0], w1 = wrow[1], w2 = wrow[2], w3 = wrow[3];
    float ak = attn[lane];

    const float4* ea4 = (const float4*)edge_attr;

    for (int e = wave; e < E_; e += nwaves) {
        int s = src[e];
        int d = dst[e];
        float4 e0 = ea4[e * 4 + 0], e1 = ea4[e * 4 + 1];
        float4 e2 = ea4[e * 4 + 2], e3 = ea4[e * 4 + 3];

        float f = A[(size_t)s * D + lane];
        f += e0.x * w0.x + e0.y * w0.y + e0.z * w0.z + e0.w * w0.w;
        f += e1.x * w1.x + e1.y * w1.y + e1.z * w1.z + e1.w * w1.w;
        f += e2.x * w2.x + e2.y * w2.y + e2.z * w2.z + e2.w * w2.w;
        f += e3.x * w3.x + e3.y * w3.y + e3.z * w3.z + e3.w * w3.w;

        float v = leaky(f) * ak;
#pragma unroll
        for (int off = 32; off > 0; off >>= 1) v += __shfl_xor(v, off, 64);

        if (lane == 0) p[e] = __expf(v + r[d]);
    }
}

// ---------------- Kernel 3: atomic-free aggregation + finalize ----------------
// wave per dst node: out[n] = (sum_j p_j * xt[src_j]) / (sum_j p_j) + bias
__global__ __launch_bounds__(256) void agg_kernel(
    const int* __restrict__ offs, const int* __restrict__ srcp,
    const int* __restrict__ eid, const float* __restrict__ p,
    const float* __restrict__ xt, const float* __restrict__ bias,
    float* __restrict__ out, int N_)
{
    const int lane   = threadIdx.x & 63;
    const int wave   = blockIdx.x * (blockDim.x >> 6) + (threadIdx.x >> 6);
    const int nwaves = gridDim.x * (blockDim.x >> 6);
    float bk = bias[lane];

    for (int n = wave; n < N_; n += nwaves) {
        int beg = offs[n], end = offs[n + 1];
        float acc = 0.f, psum = 0.f;
        for (int j = beg; j < end; j++) {
            int   s  = srcp[j];
            float pe = p[eid[j]];
            acc  += pe * xt[(size_t)s * D + lane];
            psum += pe;
        }
        float sc = psum > 0.f ? 1.f / psum : 0.f;
        out[(size_t)n * D + lane] = acc * sc + bk;
    }
}

extern "C" void kernel_launch(void* const* d_in, const int* in_sizes, int n_in,
                              void* d_out, int out_size, void* d_ws, size_t ws_size,
                              hipStream_t stream)
{
    const float* x         = (const float*)d_in[0];
    const float* edge_attr = (const float*)d_in[1];
    const int*   src       = (const int*)d_in[2];
    const int*   dst       = (const int*)d_in[3];
    const float* W1        = (const float*)d_in[4];
    const float* W2        = (const float*)d_in[5];
    const float* attn      = (const float*)d_in[6];
    const float* bias      = (const float*)d_in[7];
    float* out = (float*)d_out;

    const int N_ = in_sizes[0] / D;   // 100000
    const int E_ = in_sizes[2];       // 1280000

    // workspace layout (4B units):
    // A[N*64] | xt[N*64] | r[N] | p[E] | srcp[E] | eid[E] | counts[N] | offs[N+1] | cursor[N] | partials[512]
    float* A        = (float*)d_ws;
    float* xt       = A  + (size_t)N_ * D;
    float* r        = xt + (size_t)N_ * D;
    float* p        = r  + N_;
    int*   srcp     = (int*)(p + E_);
    int*   eid      = srcp + E_;
    int*   counts   = eid + E_;
    int*   offs     = counts + N_;
    int*   cursor   = offs + (N_ + 1);
    int*   partials = cursor + N_;

    const int nScanBlocks = (N_ + 255) / 256;   // 391 <= 512
    const int eBlocks     = (E_ + 255) / 256;

    hipMemsetAsync(counts, 0, (size_t)N_ * sizeof(int), stream);

    node_kernel<<<(N_ + 255) / 256, 256, 0, stream>>>(x, W1, W2, attn, A, xt, r, N_);
    hist_kernel<<<eBlocks, 256, 0, stream>>>(dst, counts, E_);
    scan1_kernel<<<nScanBlocks, 256, 0, stream>>>(counts, offs, partials, N_);
    scan2_kernel<<<1, 512, 0, stream>>>(partials, nScanBlocks);
    scan3_kernel<<<nScanBlocks, 256, 0, stream>>>(counts, offs, partials, cursor, N_);
    scatter_kernel<<<eBlocks, 256, 0, stream>>>(src, dst, cursor, srcp, eid, E_);
    p_kernel<<<8192, 256, 0, stream>>>(edge_attr, src, dst, W1, attn, A, r, p, E_);
    agg_kernel<<<25000, 256, 0, stream>>>(offs, srcp, eid, p, xt, bias, out, N_);
}

// Round 3
// 689.006 us; speedup vs baseline: 1.2122x; 1.2122x over previous
//
#include <hip/hip_runtime.h>

#define D 64          // D_IN == D_OUT
#define D_EDGE 16
#define NEG 0.01f

__device__ __forceinline__ float leaky(float v) { return v > 0.f ? v : NEG * v; }

// ---------------- Kernel 1: per-node precompute ----------------
//   x_t[n] = x[n] @ W2.T          (W2 [64][64])
//   A[n]   = x[n] @ W1[:, :64].T  (W1 [64][80], cols 0..63)
//   r[n]   = sum_j leaky(x[n][j]) * attn[64+j]
__global__ __launch_bounds__(256) void node_kernel(
    const float* __restrict__ x, const float* __restrict__ W1,
    const float* __restrict__ W2, const float* __restrict__ attn,
    float* __restrict__ A, float* __restrict__ xt, float* __restrict__ r, int N_)
{
    __shared__ float w2s[64 * 64];
    __shared__ float w1s[64 * 64];
    __shared__ float ah[64];
    for (int i = threadIdx.x; i < 64 * 64; i += 256) {
        w2s[i] = W2[i];
        int k = i >> 6, j = i & 63;
        w1s[i] = W1[k * 80 + j];
    }
    if (threadIdx.x < 64) ah[threadIdx.x] = attn[64 + threadIdx.x];
    __syncthreads();

    int n = blockIdx.x * 256 + threadIdx.x;
    if (n >= N_) return;

    const float4* x4 = (const float4*)(x + (size_t)n * D);
    float4 xr[16];
#pragma unroll
    for (int i = 0; i < 16; i++) xr[i] = x4[i];

    const float4* w2s4 = (const float4*)w2s;
    const float4* w1s4 = (const float4*)w1s;
    for (int k = 0; k < 64; k++) {
        float a = 0.f, b = 0.f;
#pragma unroll
        for (int j = 0; j < 16; j++) {
            float4 w = w2s4[k * 16 + j];
            a += xr[j].x * w.x + xr[j].y * w.y + xr[j].z * w.z + xr[j].w * w.w;
            float4 u = w1s4[k * 16 + j];
            b += xr[j].x * u.x + xr[j].y * u.y + xr[j].z * u.z + xr[j].w * u.w;
        }
        xt[(size_t)n * D + k] = a;
        A[(size_t)n * D + k]  = b;
    }

    float rr = 0.f;
#pragma unroll
    for (int j = 0; j < 16; j++) {
        rr += leaky(xr[j].x) * ah[4 * j + 0];
        rr += leaky(xr[j].y) * ah[4 * j + 1];
        rr += leaky(xr[j].z) * ah[4 * j + 2];
        rr += leaky(xr[j].w) * ah[4 * j + 3];
    }
    r[n] = rr;
}

// ---------------- CSR build (hist + 3-step scan) ----------------
__global__ __launch_bounds__(256) void hist_kernel(
    const int* __restrict__ dst, int* __restrict__ counts, int E_)
{
    int e = blockIdx.x * 256 + threadIdx.x;
    if (e < E_) atomicAdd(&counts[dst[e]], 1);
}

__global__ __launch_bounds__(256) void scan1_kernel(
    const int* __restrict__ counts, int* __restrict__ offs,
    int* __restrict__ partials, int N_)
{
    __shared__ int tmp[256];
    int i = blockIdx.x * 256 + threadIdx.x;
    int v = (i < N_) ? counts[i] : 0;
    tmp[threadIdx.x] = v;
    __syncthreads();
    for (int off = 1; off < 256; off <<= 1) {
        int t = (threadIdx.x >= off) ? tmp[threadIdx.x - off] : 0;
        __syncthreads();
        tmp[threadIdx.x] += t;
        __syncthreads();
    }
    if (i < N_) offs[i + 1] = tmp[threadIdx.x];
    if (threadIdx.x == 255) partials[blockIdx.x] = tmp[255];
}

__global__ __launch_bounds__(512) void scan2_kernel(int* __restrict__ partials, int nparts)
{
    __shared__ int tmp[512];
    int t = threadIdx.x;
    int v = (t < nparts) ? partials[t] : 0;
    tmp[t] = v;
    __syncthreads();
    for (int off = 1; off < 512; off <<= 1) {
        int a = (t >= off) ? tmp[t - off] : 0;
        __syncthreads();
        tmp[t] += a;
        __syncthreads();
    }
    if (t < nparts) partials[t] = (t > 0) ? tmp[t - 1] : 0;
}

__global__ __launch_bounds__(256) void scan3_kernel(
    const int* __restrict__ counts, int* __restrict__ offs,
    const int* __restrict__ partials, int* __restrict__ cursor, int N_)
{
    int i = blockIdx.x * 256 + threadIdx.x;
    if (i < N_) {
        int incl = offs[i + 1] + partials[blockIdx.x];
        offs[i + 1] = incl;
        cursor[i] = incl - counts[i];
        if (i == 0) offs[0] = 0;
    }
}

// ---------------- Kernel 2: per-edge attention, x4 ILP, fused scatter -------
// wave handles 4 consecutive edges per iteration; writes p directly into
// dst-sorted position via ticket atomics (replaces the separate scatter pass).
#define EDOT(i, fa, vout) {                                                   \
    float4 a0 = ea4[(size_t)(base + i) * 4 + 0];                              \
    float4 a1 = ea4[(size_t)(base + i) * 4 + 1];                              \
    float4 a2 = ea4[(size_t)(base + i) * 4 + 2];                              \
    float4 a3 = ea4[(size_t)(base + i) * 4 + 3];                              \
    float g = a0.x*w0.x + a0.y*w0.y + a0.z*w0.z + a0.w*w0.w                   \
            + a1.x*w1.x + a1.y*w1.y + a1.z*w1.z + a1.w*w1.w                   \
            + a2.x*w2.x + a2.y*w2.y + a2.z*w2.z + a2.w*w2.w                   \
            + a3.x*w3.x + a3.y*w3.y + a3.z*w3.z + a3.w*w3.w;                  \
    vout = leaky(fa + g) * ak; }

__global__ __launch_bounds__(256) void p_kernel(
    const float* __restrict__ edge_attr, const int* __restrict__ src,
    const int* __restrict__ dst, const float* __restrict__ W1,
    const float* __restrict__ attn,
    const float* __restrict__ A, const float* __restrict__ r,
    int* __restrict__ cursor, int* __restrict__ srcp, float* __restrict__ ps,
    int E_)
{
    const int lane = threadIdx.x & 63;
    const int wid  = __builtin_amdgcn_readfirstlane(threadIdx.x >> 6); // uniform
    const int wave = blockIdx.x * 4 + wid;
    const int nw   = gridDim.x * 4;

    const float4* wrow = (const float4*)(W1 + lane * 80 + 64);
    float4 w0 = wrow[0], w1 = wrow[1], w2 = wrow[2], w3 = wrow[3];
    float ak = attn[lane];
    const float4* ea4 = (const float4*)edge_attr;

    int base = wave * 4;
    for (; base + 4 <= E_; base += nw * 4) {
        // uniform scalar loads (4 consecutive → s_load_dwordx4)
        int s0 = src[base + 0], s1 = src[base + 1], s2 = src[base + 2], s3 = src[base + 3];
        int d0 = dst[base + 0], d1 = dst[base + 1], d2 = dst[base + 2], d3 = dst[base + 3];
        // 4 independent A-row gathers in flight
        float fa0 = A[(size_t)s0 * D + lane];
        float fa1 = A[(size_t)s1 * D + lane];
        float fa2 = A[(size_t)s2 * D + lane];
        float fa3 = A[(size_t)s3 * D + lane];
        float r0 = r[d0], r1 = r[d1], r2 = r[d2], r3 = r[d3];

        float v0, v1, v2, v3;
        EDOT(0, fa0, v0)
        EDOT(1, fa1, v1)
        EDOT(2, fa2, v2)
        EDOT(3, fa3, v3)

        // 4 interleaved butterfly reductions — independent chains pipeline
#pragma unroll
        for (int off = 32; off > 0; off >>= 1) {
            v0 += __shfl_xor(v0, off, 64);
            v1 += __shfl_xor(v1, off, 64);
            v2 += __shfl_xor(v2, off, 64);
            v3 += __shfl_xor(v3, off, 64);
        }

        if (lane < 4) {
            float pv; int dd, ss;
            if      (lane == 0) { pv = __expf(v0 + r0); dd = d0; ss = s0; }
            else if (lane == 1) { pv = __expf(v1 + r1); dd = d1; ss = s1; }
            else if (lane == 2) { pv = __expf(v2 + r2); dd = d2; ss = s2; }
            else                { pv = __expf(v3 + r3); dd = d3; ss = s3; }
            int j = atomicAdd(&cursor[dd], 1);
            srcp[j] = ss;
            ps[j]   = pv;
        }
    }
    // tail (E_ % 4 leftovers)
    if (base < E_) {
        for (int e = base; e < E_; e++) {
            int s = src[e], d = dst[e];
            float fa = A[(size_t)s * D + lane];
            float4 a0 = ea4[(size_t)e * 4 + 0], a1 = ea4[(size_t)e * 4 + 1];
            float4 a2 = ea4[(size_t)e * 4 + 2], a3 = ea4[(size_t)e * 4 + 3];
            float g = a0.x*w0.x + a0.y*w0.y + a0.z*w0.z + a0.w*w0.w
                    + a1.x*w1.x + a1.y*w1.y + a1.z*w1.z + a1.w*w1.w
                    + a2.x*w2.x + a2.y*w2.y + a2.z*w2.z + a2.w*w2.w
                    + a3.x*w3.x + a3.y*w3.y + a3.z*w3.z + a3.w*w3.w;
            float v = leaky(fa + g) * ak;
#pragma unroll
            for (int off = 32; off > 0; off >>= 1) v += __shfl_xor(v, off, 64);
            if (lane == 0) {
                int j = atomicAdd(&cursor[d], 1);
                srcp[j] = s;
                ps[j]   = __expf(v + r[d]);
            }
        }
    }
}

// ---------------- Kernel 3: aggregation + finalize (atomic-free) ------------
// wave per dst node; srcp/ps reads are sequential (coalesced), 4 xt-gathers
// in flight per iteration.
__global__ __launch_bounds__(256) void agg_kernel(
    const int* __restrict__ offs, const int* __restrict__ srcp,
    const float* __restrict__ ps, const float* __restrict__ xt,
    const float* __restrict__ bias, float* __restrict__ out, int N_)
{
    const int lane = threadIdx.x & 63;
    const int wid  = __builtin_amdgcn_readfirstlane(threadIdx.x >> 6);
    const int wave = blockIdx.x * 4 + wid;
    const int nw   = gridDim.x * 4;
    float bk = bias[lane];

    for (int n = wave; n < N_; n += nw) {
        int beg = offs[n], end = offs[n + 1];  // uniform → scalar loads
        float acc = 0.f, psum = 0.f;
        int j = beg;
        for (; j + 4 <= end; j += 4) {
            int   s0 = srcp[j], s1 = srcp[j+1], s2 = srcp[j+2], s3 = srcp[j+3];
            float p0 = ps[j],   p1 = ps[j+1],   p2 = ps[j+2],   p3 = ps[j+3];
            float x0 = xt[(size_t)s0 * D + lane];
            float x1 = xt[(size_t)s1 * D + lane];
            float x2 = xt[(size_t)s2 * D + lane];
            float x3 = xt[(size_t)s3 * D + lane];
            acc = fmaf(p0, x0, acc); acc = fmaf(p1, x1, acc);
            acc = fmaf(p2, x2, acc); acc = fmaf(p3, x3, acc);
            psum += p0 + p1 + p2 + p3;
        }
        for (; j < end; j++) {
            int s = srcp[j]; float pe = ps[j];
            acc = fmaf(pe, xt[(size_t)s * D + lane], acc);
            psum += pe;
        }
        float sc = psum > 0.f ? 1.f / psum : 0.f;
        out[(size_t)n * D + lane] = fmaf(acc, sc, bk);
    }
}

extern "C" void kernel_launch(void* const* d_in, const int* in_sizes, int n_in,
                              void* d_out, int out_size, void* d_ws, size_t ws_size,
                              hipStream_t stream)
{
    const float* x         = (const float*)d_in[0];
    const float* edge_attr = (const float*)d_in[1];
    const int*   src       = (const int*)d_in[2];
    const int*   dst       = (const int*)d_in[3];
    const float* W1        = (const float*)d_in[4];
    const float* W2        = (const float*)d_in[5];
    const float* attn      = (const float*)d_in[6];
    const float* bias      = (const float*)d_in[7];
    float* out = (float*)d_out;

    const int N_ = in_sizes[0] / D;   // 100000
    const int E_ = in_sizes[2];       // 1280000

    // workspace (4B units):
    // A[N*64] | xt[N*64] | r[N] | srcp[E] | ps[E] | counts[N] | offs[N+1] | cursor[N] | partials[512]
    float* A        = (float*)d_ws;
    float* xt       = A  + (size_t)N_ * D;
    float* r        = xt + (size_t)N_ * D;
    int*   srcp     = (int*)(r + N_);
    float* ps       = (float*)(srcp + E_);
    int*   counts   = (int*)(ps + E_);
    int*   offs     = counts + N_;
    int*   cursor   = offs + (N_ + 1);
    int*   partials = cursor + N_;

    const int nScanBlocks = (N_ + 255) / 256;   // 391 <= 512
    const int eBlocks     = (E_ + 255) / 256;

    hipMemsetAsync(counts, 0, (size_t)N_ * sizeof(int), stream);

    node_kernel<<<(N_ + 255) / 256, 256, 0, stream>>>(x, W1, W2, attn, A, xt, r, N_);
    hist_kernel<<<eBlocks, 256, 0, stream>>>(dst, counts, E_);
    scan1_kernel<<<nScanBlocks, 256, 0, stream>>>(counts, offs, partials, N_);
    scan2_kernel<<<1, 512, 0, stream>>>(partials, nScanBlocks);
    scan3_kernel<<<nScanBlocks, 256, 0, stream>>>(counts, offs, partials, cursor, N_);
    p_kernel<<<2048, 256, 0, stream>>>(edge_attr, src, dst, W1, attn, A, r,
                                       cursor, srcp, ps, E_);
    agg_kernel<<<2048, 256, 0, stream>>>(offs, srcp, ps, xt, bias, out, N_);
}

// Round 4
// 601.654 us; speedup vs baseline: 1.3882x; 1.1452x over previous
//
#include <hip/hip_runtime.h>

#define D 64          // D_IN == D_OUT
#define D_EDGE 16
#define NEG 0.01f

__device__ __forceinline__ float leaky(float v) { return v > 0.f ? v : NEG * v; }

// ---------------- Kernel 1: per-node precompute ----------------
//   x_t[n] = x[n] @ W2.T          (W2 [64][64])
//   A[n]   = x[n] @ W1[:, :64].T  (W1 [64][80], cols 0..63)
//   r[n]   = sum_j leaky(x[n][j]) * attn[64+j]
__global__ __launch_bounds__(256) void node_kernel(
    const float* __restrict__ x, const float* __restrict__ W1,
    const float* __restrict__ W2, const float* __restrict__ attn,
    float* __restrict__ A, float* __restrict__ xt, float* __restrict__ r, int N_)
{
    __shared__ float w2s[64 * 64];
    __shared__ float w1s[64 * 64];
    __shared__ float ah[64];
    for (int i = threadIdx.x; i < 64 * 64; i += 256) {
        w2s[i] = W2[i];
        int k = i >> 6, j = i & 63;
        w1s[i] = W1[k * 80 + j];
    }
    if (threadIdx.x < 64) ah[threadIdx.x] = attn[64 + threadIdx.x];
    __syncthreads();

    int n = blockIdx.x * 256 + threadIdx.x;
    if (n >= N_) return;

    const float4* x4 = (const float4*)(x + (size_t)n * D);
    float4 xr[16];
#pragma unroll
    for (int i = 0; i < 16; i++) xr[i] = x4[i];

    const float4* w2s4 = (const float4*)w2s;
    const float4* w1s4 = (const float4*)w1s;
    for (int k = 0; k < 64; k++) {
        float a = 0.f, b = 0.f;
#pragma unroll
        for (int j = 0; j < 16; j++) {
            float4 w = w2s4[k * 16 + j];
            a += xr[j].x * w.x + xr[j].y * w.y + xr[j].z * w.z + xr[j].w * w.w;
            float4 u = w1s4[k * 16 + j];
            b += xr[j].x * u.x + xr[j].y * u.y + xr[j].z * u.z + xr[j].w * u.w;
        }
        xt[(size_t)n * D + k] = a;
        A[(size_t)n * D + k]  = b;
    }

    float rr = 0.f;
#pragma unroll
    for (int j = 0; j < 16; j++) {
        rr += leaky(xr[j].x) * ah[4 * j + 0];
        rr += leaky(xr[j].y) * ah[4 * j + 1];
        rr += leaky(xr[j].z) * ah[4 * j + 2];
        rr += leaky(xr[j].w) * ah[4 * j + 3];
    }
    r[n] = rr;
}

// ---------------- Kernel 2: fused edge kernel, half-wave per edge ----------
// Wave handles 2 edges (e0 = 2*pair, e1 = e0+1). Lane l: half = l>>5,
// k0 = (l&31)*2 — lane owns logits-k {k0,k0+1} of its half's edge.
//   f_k   = A[src][k] + ea[e]·W1[k,64:80]
//   v     = leaky(f_k0)*attn[k0] + leaky(f_k1)*attn[k1], butterfly over 32
//   p     = exp(v_sum + r[dst])
//   denom[dst] += p;  out[dst][lane] += p * xt[src][lane]   (full wave/edge)
__global__ __launch_bounds__(256) void edge_kernel(
    const float* __restrict__ edge_attr, const int* __restrict__ src,
    const int* __restrict__ dst, const float* __restrict__ W1,
    const float* __restrict__ attn,
    const float* __restrict__ A, const float* __restrict__ xt,
    const float* __restrict__ r,
    float* __restrict__ out, float* __restrict__ denom,
    int E_, int chunk)
{
    const int lane = threadIdx.x & 63;
    const int half = lane >> 5;
    const int k0   = (lane & 31) * 2;

    // this lane's two W1b rows (cols 64..79) + attn weights
    const float4* w1p = (const float4*)(W1 + k0 * 80 + 64);
    float4 wa0 = w1p[0], wa1 = w1p[1], wa2 = w1p[2], wa3 = w1p[3];
    const float4* w1q = (const float4*)(W1 + (k0 + 1) * 80 + 64);
    float4 wb0 = w1q[0], wb1 = w1q[1], wb2 = w1q[2], wb3 = w1q[3];
    float ak0 = attn[k0], ak1 = attn[k0 + 1];

    const int wave   = blockIdx.x * 4 + (threadIdx.x >> 6);
    const int npairs = E_ >> 1;
    int pr  = wave * chunk;
    int pe  = pr + chunk; if (pe > npairs) pe = npairs;

    for (; pr < pe; pr++) {
        const int e0 = pr * 2;
        int2 ss = *(const int2*)(src + e0);
        int2 dd = *(const int2*)(dst + e0);

        // half-specific src row, float2 of A
        int s_h = half ? ss.y : ss.x;
        float2 a2 = *(const float2*)(A + (size_t)s_h * D + k0);

        // half-specific edge_attr row (two rows are contiguous 128B)
        const float4* eap = (const float4*)(edge_attr + (size_t)(e0 + half) * D_EDGE);
        float4 q0 = eap[0], q1 = eap[1], q2 = eap[2], q3 = eap[3];

        float g0 = q0.x*wa0.x + q0.y*wa0.y + q0.z*wa0.z + q0.w*wa0.w
                 + q1.x*wa1.x + q1.y*wa1.y + q1.z*wa1.z + q1.w*wa1.w
                 + q2.x*wa2.x + q2.y*wa2.y + q2.z*wa2.z + q2.w*wa2.w
                 + q3.x*wa3.x + q3.y*wa3.y + q3.z*wa3.z + q3.w*wa3.w;
        float g1 = q0.x*wb0.x + q0.y*wb0.y + q0.z*wb0.z + q0.w*wb0.w
                 + q1.x*wb1.x + q1.y*wb1.y + q1.z*wb1.z + q1.w*wb1.w
                 + q2.x*wb2.x + q2.y*wb2.y + q2.z*wb2.z + q2.w*wb2.w
                 + q3.x*wb3.x + q3.y*wb3.y + q3.z*wb3.z + q3.w*wb3.w;

        float v = leaky(a2.x + g0) * ak0 + leaky(a2.y + g1) * ak1;

        // butterfly within each 32-lane half (xor masks < 32 don't cross halves)
#pragma unroll
        for (int off = 16; off > 0; off >>= 1) v += __shfl_xor(v, off, 64);
        // exchange: every lane gets both halves' sums
        float vo = __shfl_xor(v, 32, 64);
        float vA = half ? vo : v;
        float vB = half ? v : vo;

        float pA = __expf(vA + r[dd.x]);
        float pB = __expf(vB + r[dd.y]);

        // aggregation: full wave per edge, lane = output channel
        float mA = xt[(size_t)ss.x * D + lane];
        float mB = xt[(size_t)ss.y * D + lane];
        atomicAdd(out + (size_t)dd.x * D + lane, pA * mA);
        atomicAdd(out + (size_t)dd.y * D + lane, pB * mB);
        if (lane == 0)       atomicAdd(denom + dd.x, pA);
        else if (lane == 32) atomicAdd(denom + dd.y, pB);
    }

    // tail: odd E_ (not the case here, but stay correct)
    if (wave == 0 && (E_ & 1)) {
        int e = E_ - 1;
        int s = src[e], d = dst[e];
        float2 a2 = *(const float2*)(A + (size_t)s * D + k0);
        const float4* eap = (const float4*)(edge_attr + (size_t)e * D_EDGE);
        float4 q0 = eap[0], q1 = eap[1], q2 = eap[2], q3 = eap[3];
        float g0 = q0.x*wa0.x + q0.y*wa0.y + q0.z*wa0.z + q0.w*wa0.w
                 + q1.x*wa1.x + q1.y*wa1.y + q1.z*wa1.z + q1.w*wa1.w
                 + q2.x*wa2.x + q2.y*wa2.y + q2.z*wa2.z + q2.w*wa2.w
                 + q3.x*wa3.x + q3.y*wa3.y + q3.z*wa3.z + q3.w*wa3.w;
        float g1 = q0.x*wb0.x + q0.y*wb0.y + q0.z*wb0.z + q0.w*wb0.w
                 + q1.x*wb1.x + q1.y*wb1.y + q1.z*wb1.z + q1.w*wb1.w
                 + q2.x*wb2.x + q2.y*wb2.y + q2.z*wb2.z + q2.w*wb2.w
                 + q3.x*wb3.x + q3.y*wb3.y + q3.z*wb3.z + q3.w*wb3.w;
        float v = leaky(a2.x + g0) * ak0 + leaky(a2.y + g1) * ak1;
#pragma unroll
        for (int off = 32; off > 0; off >>= 1) v += __shfl_xor(v, off, 64);
        float p = __expf(v + r[d]);
        atomicAdd(out + (size_t)d * D + lane, p * xt[(size_t)s * D + lane]);
        if (lane == 0) atomicAdd(denom + d, p);
    }
}

// ---------------- Kernel 3: normalize + bias ----------------
__global__ __launch_bounds__(256) void fin_kernel(
    float* __restrict__ out, const float* __restrict__ denom,
    const float* __restrict__ bias, int total)
{
    int i = blockIdx.x * 256 + threadIdx.x;
    if (i >= total) return;
    int n = i >> 6, k = i & 63;
    float dn = denom[n];
    float sc = dn > 0.f ? 1.f / dn : 0.f;
    out[i] = fmaf(out[i], sc, bias[k]);
}

extern "C" void kernel_launch(void* const* d_in, const int* in_sizes, int n_in,
                              void* d_out, int out_size, void* d_ws, size_t ws_size,
                              hipStream_t stream)
{
    const float* x         = (const float*)d_in[0];
    const float* edge_attr = (const float*)d_in[1];
    const int*   src       = (const int*)d_in[2];
    const int*   dst       = (const int*)d_in[3];
    const float* W1        = (const float*)d_in[4];
    const float* W2        = (const float*)d_in[5];
    const float* attn      = (const float*)d_in[6];
    const float* bias      = (const float*)d_in[7];
    float* out = (float*)d_out;

    const int N_ = in_sizes[0] / D;   // 100000
    const int E_ = in_sizes[2];       // 1280000

    // workspace (fp32): A[N*64] | xt[N*64] | r[N] | denom[N]
    float* A     = (float*)d_ws;
    float* xt    = A  + (size_t)N_ * D;
    float* r     = xt + (size_t)N_ * D;
    float* denom = r  + N_;

    hipMemsetAsync(out,   0, (size_t)out_size * sizeof(float), stream);
    hipMemsetAsync(denom, 0, (size_t)N_ * sizeof(float), stream);

    node_kernel<<<(N_ + 255) / 256, 256, 0, stream>>>(x, W1, W2, attn, A, xt, r, N_);

    const int eBlocks = 8192;
    const int nwaves  = eBlocks * 4;
    const int npairs  = E_ >> 1;
    const int chunk   = (npairs + nwaves - 1) / nwaves;   // contiguous pairs per wave
    edge_kernel<<<eBlocks, 256, 0, stream>>>(edge_attr, src, dst, W1, attn,
                                             A, xt, r, out, denom, E_, chunk);

    fin_kernel<<<((size_t)N_ * D + 255) / 256, 256, 0, stream>>>(out, denom, bias, N_ * D);
}